// Round 5
// baseline (1193.453 us; speedup 1.0000x reference)
//
#include <hip/hip_runtime.h>
#include <stdint.h>

#define B_   128
#define T_   500
#define C_   700
#define CP_  704          // C padded to 16
#define H_   1024
#define O_   20
#define M_   (T_ * B_)    // 64000 rows, row = t*128 + b
#define KA_  (2 * CP_)    // 1408: A' = [hi | lo]
#define KB_  (3 * CP_)    // 2112: Bt = [hi | hi | lo]
#define NKSTEP_ (KB_ / 64)   // 33 K-steps of 64
#define SCALE_      256.0f
#define INV_SCALE2_ (1.0f / 65536.0f)
#define MAXD_ 30
#define TT_   20                       // t-rows produced per delay block
#define RR_   (TT_ + MAXD_)            // 50 source rows staged in LDS
#define CS_   176                      // channels per delay block (4-way split)
#define LSTR_ 180                      // LDS row stride: 720B = 16B-aligned,
                                       // 180%32=20 -> 8-position bank spread

typedef _Float16 half8 __attribute__((ext_vector_type(8)));
typedef float    f32x4 __attribute__((ext_vector_type(4)));

// ---------------------------------------------------------------------------
// out[c*R + r] = (c < C) ? in[r*C + c] : 0   (fp32 transpose, zero-pad)
// Also used to append a ZERO row (c == C) when Cpad > C: dummy-index target.
__global__ __launch_bounds__(256) void transpose_pad(
    const float* __restrict__ in, float* __restrict__ out,
    int R, int C, int Cpad) {
  int idx = blockIdx.x * 256 + threadIdx.x;
  if (idx >= Cpad * R) return;
  int c = idx / R;
  int r = idx - c * R;
  out[idx] = (c < C) ? in[(size_t)r * C + c] : 0.0f;
}

// ---------------------------------------------------------------------------
// Bt[n][k]: k in [0,704) -> hi(w*256); [704,1408) -> hi; [1408,2112) -> lo
__global__ __launch_bounds__(256) void bt_prep(
    const float* __restrict__ w_in, _Float16* __restrict__ Bt) {
  int idx = blockIdx.x * 256 + threadIdx.x;   // over H_*KB_
  if (idx >= H_ * KB_) return;
  int n = idx / KB_;
  int k = idx - n * KB_;
  int blk = k / CP_;
  int c = k - blk * CP_;
  float v = (c < C_) ? w_in[(size_t)n * C_ + c] * SCALE_ : 0.0f;
  _Float16 hi = (_Float16)v;
  Bt[idx] = (blk == 2) ? (_Float16)(v - (float)hi) : hi;
}

// ---------------------------------------------------------------------------
// R10 delay gather (FROZEN this round, control).
__global__ __launch_bounds__(512) void delay_split_lds(
    const float* __restrict__ x, const int* __restrict__ delays,
    _Float16* __restrict__ A3) {
  extern __shared__ float xs[];          // [RR_][LSTR_] floats = 36000 B
  __shared__ int sdel[CS_];

  const int b   = blockIdx.x;            // 0..127
  const int t0  = blockIdx.y * TT_;      // 0,20,...,480
  const int c0  = blockIdx.z * CS_;      // 0,176,352,528
  const int tid = threadIdx.x;

  for (int c = tid; c < CS_; c += 512) {
    const int cc = c0 + c;
    sdel[c] = (cc < C_) ? delays[cc] : 0;
  }

  const int zr = (t0 < MAXD_) ? (MAXD_ - t0) : 0;
  const float* srcb = x + ((long)(b * T_ + t0) - MAXD_) * C_ + c0;
  for (int i = tid; i < RR_ * (CS_ / 4); i += 512) {
    const int r  = i / (CS_ / 4);
    const int q4 = (i - r * (CS_ / 4)) * 4;
    float4 v = {0.f, 0.f, 0.f, 0.f};
    if (r >= zr && c0 + q4 < C_)       // 700%4==0: chunks never straddle
      v = *(const float4*)(srcb + (long)r * C_ + q4);
    *(float4*)&xs[r * LSTR_ + q4] = v;
  }
  __syncthreads();

  for (int e = tid; e < TT_ * (CS_ / 8); e += 512) {
    const int tt = e / (CS_ / 8);
    const int cl = (e - tt * (CS_ / 8)) * 8;
    half8 hv, lv;
#pragma unroll
    for (int j = 0; j < 8; ++j) {
      const int c = cl + j;
      float vv = 0.f;
      if (c0 + c < C_)
        vv = xs[(tt + MAXD_ - sdel[c]) * LSTR_ + c] * SCALE_;
      const _Float16 hi = (_Float16)vv;
      hv[j] = hi;
      lv[j] = (_Float16)(vv - (float)hi);
    }
    _Float16* dst = A3 + (size_t)((t0 + tt) * B_ + b) * KA_ + c0 + cl;
    *(half8*)dst = hv;
    *((half8*)(dst + CP_)) = lv;
  }
}

// ---------------------------------------------------------------------------
__device__ __forceinline__ void gload16(const void* g, const void* l) {
  __builtin_amdgcn_global_load_lds(
      (const __attribute__((address_space(1))) void*)(uintptr_t)g,
      (__attribute__((address_space(3))) void*)(uint32_t)(uintptr_t)l,
      16, 0, 0);
}

// ---------------------------------------------------------------------------
// R11 4-phase GEMM (FROZEN this round, control).
__global__ __launch_bounds__(512, 1) void gemm_split(
    const _Float16* __restrict__ A3, const _Float16* __restrict__ Bt,
    float* __restrict__ Cm) {
  extern __shared__ __align__(16) _Float16 lds[];   // 131072 B
  _Float16* As = lds;                // [2][256*64]
  _Float16* Bs = lds + 2 * 16384;    // [2][256*64]

  const int tid  = threadIdx.x;
  const int wave = tid >> 6, lane = tid & 63;

  const int d = blockIdx.x;
  const int g = (d & 7) * 125 + (d >> 3);
  const int row0 = (g >> 2) * 256;        // M panel (0..249)
  const int col0 = (g & 3) * 256;         // N panel (0..3)

  const int r = lane & 15, q = lane >> 4;
  const int wm = wave >> 2, wn = wave & 3;

  int asrcB[4], bsrcB[4], auoff[4];
#pragma unroll
  for (int j = 0; j < 4; ++j) {
    const int i   = j * 512 + wave * 64 + lane;
    const int row = i >> 3, c = i & 7;
    asrcB[j] = (row0 + row) * KA_ + ((c ^ (row & 7)) * 8);
    bsrcB[j] = (col0 + row) * KB_ + ((c ^ (row & 7)) * 8);
    auoff[j] = (j * 512 + wave * 64) * 8;   // wave-uniform LDS base (halfs)
  }

  int aRow[8], bRow[4];
#pragma unroll
  for (int m = 0; m < 8; ++m) aRow[m] = (wm * 128 + m * 16 + r) * 64;
#pragma unroll
  for (int n = 0; n < 4; ++n) bRow[n] = (wn * 64 + n * 16 + r) * 64;
  const int sl0 = (q ^ (r & 7)) * 8;      // ks=0 slot
  const int sl1 = sl0 ^ 32;               // ks=1 slot

  f32x4 acc[8][4] = {};

#pragma unroll
  for (int j = 0; j < 4; ++j) gload16(A3 + asrcB[j], As + auoff[j]);
#pragma unroll
  for (int j = 0; j < 4; ++j) gload16(Bt + bsrcB[j], Bs + auoff[j]);
  asm volatile("s_waitcnt vmcnt(0)" ::: "memory");
  __syncthreads();

#define PHASE_BAR() do {                                   \
    __builtin_amdgcn_sched_barrier(0);                     \
    __builtin_amdgcn_s_barrier();                          \
    __builtin_amdgcn_sched_barrier(0);                     \
  } while (0)

#define MFMA16(AF, BF) do {                                \
    __builtin_amdgcn_s_setprio(1);                         \
    _Pragma("unroll")                                      \
    for (int mm = 0; mm < 4; ++mm)                         \
      _Pragma("unroll")                                    \
      for (int nn = 0; nn < 4; ++nn)                       \
        ACCROW[mm][nn] = __builtin_amdgcn_mfma_f32_16x16x32_f16( \
            AF[mm], BF[nn], ACCROW[mm][nn], 0, 0, 0);      \
    __builtin_amdgcn_s_setprio(0);                         \
  } while (0)

  for (int k = 0; k < NKSTEP_; ++k) {
    const int cbuf = (k & 1) * 16384;
    const int nbuf = ((k + 1) & 1) * 16384;
    const int k0n  = (k + 1) * 64;
    const int kAn  = (k0n < KA_) ? k0n : k0n - KA_;
    const bool st  = (k + 1 < NKSTEP_);

    half8 a0[4], a1[4], b0[4], b1[4];

#pragma unroll
    for (int m = 0; m < 4; ++m) a0[m] = *(const half8*)&As[cbuf + aRow[m] + sl0];
#pragma unroll
    for (int n = 0; n < 4; ++n) b0[n] = *(const half8*)&Bs[cbuf + bRow[n] + sl0];
    if (st) {
#pragma unroll
      for (int j = 0; j < 4; ++j) gload16(A3 + asrcB[j] + kAn, As + nbuf + auoff[j]);
    }
    PHASE_BAR();
    {
      f32x4 (&ACCROW)[4][4] = *reinterpret_cast<f32x4(*)[4][4]>(&acc[0]);
      MFMA16(a0, b0);
    }
    PHASE_BAR();

#pragma unroll
    for (int m = 0; m < 4; ++m) a1[m] = *(const half8*)&As[cbuf + aRow[m + 4] + sl0];
    if (st) {
      gload16(Bt + bsrcB[0] + k0n, Bs + nbuf + auoff[0]);
      gload16(Bt + bsrcB[1] + k0n, Bs + nbuf + auoff[1]);
    }
    PHASE_BAR();
    {
      f32x4 (&ACCROW)[4][4] = *reinterpret_cast<f32x4(*)[4][4]>(&acc[4]);
      MFMA16(a1, b0);
    }
    PHASE_BAR();

#pragma unroll
    for (int m = 0; m < 4; ++m) a0[m] = *(const half8*)&As[cbuf + aRow[m] + sl1];
#pragma unroll
    for (int n = 0; n < 4; ++n) b1[n] = *(const half8*)&Bs[cbuf + bRow[n] + sl1];
    if (st) {
      gload16(Bt + bsrcB[2] + k0n, Bs + nbuf + auoff[2]);
      gload16(Bt + bsrcB[3] + k0n, Bs + nbuf + auoff[3]);
    }
    PHASE_BAR();
    {
      f32x4 (&ACCROW)[4][4] = *reinterpret_cast<f32x4(*)[4][4]>(&acc[0]);
      MFMA16(a0, b1);
    }
    PHASE_BAR();

#pragma unroll
    for (int m = 0; m < 4; ++m) a1[m] = *(const half8*)&As[cbuf + aRow[m + 4] + sl1];
    PHASE_BAR();
    {
      f32x4 (&ACCROW)[4][4] = *reinterpret_cast<f32x4(*)[4][4]>(&acc[4]);
      MFMA16(a1, b1);
    }
    asm volatile("s_waitcnt vmcnt(0)" ::: "memory");
    PHASE_BAR();
  }
#undef MFMA16
#undef PHASE_BAR

#pragma unroll
  for (int m = 0; m < 8; ++m) {
    const int mrow = row0 + wm * 128 + m * 16 + q * 4;
#pragma unroll
    for (int n = 0; n < 4; ++n) {
      const int ncol = col0 + wn * 64 + n * 16 + r;
      float* cp = Cm + (size_t)mrow * H_ + ncol;
#pragma unroll
      for (int rg = 0; rg < 4; ++rg)
        cp[(size_t)rg * H_] = acc[m][n][rg] * INV_SCALE2_;
    }
  }
}

// ---------------------------------------------------------------------------
// R12 recurrent: LDS spike-index list replaces the ballot/readlane scan.
// 512 threads (8 waves), 2 neurons/thread (h = tid*2 + j). Per step:
//   gather: iterate 8 per-wave lists (uniform counts), 8 indices/iter read
//           as 2x ushort4 LDS broadcast; 8x float2 wrec loads + 16 FMA.
//           No serial SALU chain -- iterations pipeline freely.
//   LIF -> nib (2 bits); compact via 2-ballot prefix (popcll of masked
//           ballots, ~8 VALU); pad list to x8 with dummy index 1024 which
//           targets an appended ZERO row of wrecT/woutT (tail is free).
//   One barrier/step, double-buffered lists.
__global__ __launch_bounds__(512, 1) void recurrent_w(
    const float* __restrict__ Iin,   // [M_][H_], row = t*128 + b
    const float* __restrict__ wrecT, // [(H_+1)][H_], row 1024 = zeros
    const float* __restrict__ woutT, // [(H_+1)][O_], row 1024 = zeros
    const float* __restrict__ alpha, const float* __restrict__ rho,
    const float* __restrict__ beta_a, const float* __restrict__ beta_out,
    float* __restrict__ out) {
  const int b    = blockIdx.x;
  const int tid  = threadIdx.x;     // 0..511
  const int wv   = tid >> 6, lane = tid & 63;
  const int h0   = tid * 2;         // 2 columns per thread

  __shared__ unsigned short slist[2][8][136];  // per-wave spike lists
  __shared__ int scnt[2][8];                   // padded counts (x8)

  float vv0 = 0.f, vv1 = 0.f, av0 = 0.f, av1 = 0.f;
  unsigned pnib = 0u;               // this thread's own 2 prev-spike bits

  const float al = alpha[h0], al1 = 1.0f - al;
  const float rh = rho[h0],   rh1 = 1.0f - rh;
  const float ba = beta_a[h0];

  const int olane = (tid < O_) ? tid : 0;
  float bo = 0.f, vo = 0.f, osum = 0.f;
  if (tid < O_) bo = beta_out[tid];

  if (tid < 16) scnt[tid >> 3][tid & 7] = 0;   // zero both buffers
  __syncthreads();

  const float* base = Iin + (size_t)b * H_ + h0;

  // prime 4-deep Iin prefetch: one float2 per t = 0,1,2,3
  float2 pA = *(const float2*)(base + (size_t)0 * (B_ * H_));
  float2 pB = *(const float2*)(base + (size_t)1 * (B_ * H_));
  float2 pC = *(const float2*)(base + (size_t)2 * (B_ * H_));
  float2 pD = *(const float2*)(base + (size_t)3 * (B_ * H_));

  int cb = 0;

#define LIF_STEP(NR, TCUR)                                                    \
  {                                                                           \
    float I0 = NR.x, I1 = NR.y, io = 0.f;                                     \
    _Pragma("unroll")                                                         \
    for (int w = 0; w < 8; ++w) {                                             \
      const int n = scnt[cb][w];                                              \
      const unsigned short* L = &slist[cb][w][0];                             \
      for (int i = 0; i < n; i += 8) {                                        \
        const ushort4 ia = *(const ushort4*)&L[i];                            \
        const ushort4 ib = *(const ushort4*)&L[i + 4];                        \
        const float2 w0 = *(const float2*)(wrecT + ((size_t)ia.x << 10) + h0);\
        const float2 w1 = *(const float2*)(wrecT + ((size_t)ia.y << 10) + h0);\
        const float2 w2 = *(const float2*)(wrecT + ((size_t)ia.z << 10) + h0);\
        const float2 w3 = *(const float2*)(wrecT + ((size_t)ia.w << 10) + h0);\
        const float2 w4 = *(const float2*)(wrecT + ((size_t)ib.x << 10) + h0);\
        const float2 w5 = *(const float2*)(wrecT + ((size_t)ib.y << 10) + h0);\
        const float2 w6 = *(const float2*)(wrecT + ((size_t)ib.z << 10) + h0);\
        const float2 w7 = *(const float2*)(wrecT + ((size_t)ib.w << 10) + h0);\
        const float o0 = woutT[(size_t)ia.x * O_ + olane];                    \
        const float o1 = woutT[(size_t)ia.y * O_ + olane];                    \
        const float o2 = woutT[(size_t)ia.z * O_ + olane];                    \
        const float o3 = woutT[(size_t)ia.w * O_ + olane];                    \
        const float o4 = woutT[(size_t)ib.x * O_ + olane];                    \
        const float o5 = woutT[(size_t)ib.y * O_ + olane];                    \
        const float o6 = woutT[(size_t)ib.z * O_ + olane];                    \
        const float o7 = woutT[(size_t)ib.w * O_ + olane];                    \
        I0 += ((w0.x + w1.x) + (w2.x + w3.x)) + ((w4.x + w5.x) + (w6.x + w7.x)); \
        I1 += ((w0.y + w1.y) + (w2.y + w3.y)) + ((w4.y + w5.y) + (w6.y + w7.y)); \
        io += ((o0 + o1) + (o2 + o3)) + ((o4 + o5) + (o6 + o7));              \
      }                                                                       \
    }                                                                         \
    {                                                                         \
      const int tp = ((TCUR) + 4 <= T_ - 1) ? (TCUR) + 4 : (T_ - 1);          \
      NR = *(const float2*)(base + (size_t)tp * (B_ * H_));                   \
    }                                                                         \
    vo = bo * vo + (1.0f - bo) * io;                                          \
    osum += vo;                                                               \
    const float vg0 = (pnib & 1u) ? 0.f : vv0;                                \
    const float vn0 = al * vg0 + al1 * (I0 - av0);                            \
    av0 = rh * av0 + rh1 * fmaf(ba, vn0, (vn0 > 1.0f) ? 1.0f : 0.0f);         \
    vv0 = vn0;                                                                \
    const float vg1 = (pnib & 2u) ? 0.f : vv1;                                \
    const float vn1 = al * vg1 + al1 * (I1 - av1);                            \
    av1 = rh * av1 + rh1 * fmaf(ba, vn1, (vn1 > 1.0f) ? 1.0f : 0.0f);         \
    vv1 = vn1;                                                                \
    const unsigned nib = (vn0 > 1.0f ? 1u : 0u) | (vn1 > 1.0f ? 2u : 0u);     \
    pnib = nib;                                                               \
    {                                                                         \
      const unsigned long long bl0 = __ballot(nib & 1u);                      \
      const unsigned long long bl1 = __ballot(nib & 2u);                      \
      const unsigned long long below = (1ull << lane) - 1ull;                 \
      int pos = (int)__popcll(bl0 & below) + (int)__popcll(bl1 & below);      \
      unsigned short* Lw = &slist[cb ^ 1][wv][0];                             \
      if (nib & 1u) { Lw[pos] = (unsigned short)h0; pos += 1; }               \
      if (nib & 2u) { Lw[pos] = (unsigned short)(h0 + 1); }                   \
      if (lane == 63) {                                                       \
        const int tot = (int)__popcll(bl0) + (int)__popcll(bl1);              \
        const int pd  = (tot + 7) & ~7;                                       \
        for (int z = tot; z < pd; ++z) Lw[z] = (unsigned short)H_;            \
        scnt[cb ^ 1][wv] = pd;                                                \
      }                                                                       \
    }                                                                         \
    __syncthreads();                                                          \
    cb ^= 1;                                                                  \
  }

  for (int k = 0; k < T_ / 4; ++k) {
    const int t0 = k * 4;
    LIF_STEP(pA, t0 + 0)
    LIF_STEP(pB, t0 + 1)
    LIF_STEP(pC, t0 + 2)
    LIF_STEP(pD, t0 + 3)
  }
#undef LIF_STEP

  // epilogue: readout contribution of the final spike set S(T-1)
  {
    float io = 0.f;
    for (int w = 0; w < 8; ++w) {
      const int n = scnt[cb][w];
      for (int i = 0; i < n; ++i)
        io += woutT[(size_t)slist[cb][w][i] * O_ + olane];
    }
    vo = bo * vo + (1.0f - bo) * io;
    osum += vo;
  }

  if (tid < O_) out[(size_t)b * O_ + tid] = osum / (float)T_;
}

// ---------------------------------------------------------------------------
extern "C" void kernel_launch(void* const* d_in, const int* in_sizes, int n_in,
                              void* d_out, int out_size, void* d_ws, size_t ws_size,
                              hipStream_t stream) {
  const float* x        = (const float*)d_in[0];
  const int*   delays   = (const int*)d_in[1];
  const float* w_in     = (const float*)d_in[2];
  const float* w_rec    = (const float*)d_in[3];
  const float* w_out    = (const float*)d_in[4];
  const float* alpha    = (const float*)d_in[5];
  const float* rho      = (const float*)d_in[6];
  const float* beta_a   = (const float*)d_in[7];
  const float* beta_out = (const float*)d_in[8];

  float* ws    = (float*)d_ws;
  float* wrecT = ws;                                      // (H+1)*H fp32
  float* woutT = wrecT + (size_t)(H_ + 1) * H_;           // (H+1)*O fp32
  float* Iin   = woutT + (size_t)(H_ + 1) * O_;           // M*H fp32
  _Float16* A3 = (_Float16*)(Iin + (size_t)M_ * H_);      // M*KA fp16
  _Float16* Bt = A3 + (size_t)M_ * KA_;                   // H*KB fp16
  float* out   = (float*)d_out;

  // Cpad = H_+1 appends a zero row at index 1024 (dummy-index target).
  transpose_pad<<<((H_ + 1) * H_) / 256, 256, 0, stream>>>(
      w_rec, wrecT, H_, H_, H_ + 1);
  transpose_pad<<<((H_ + 1) * O_ + 255) / 256, 256, 0, stream>>>(
      w_out, woutT, O_, H_, H_ + 1);
  bt_prep<<<(H_ * KB_) / 256, 256, 0, stream>>>(w_in, Bt);

  dim3 gd(B_, T_ / TT_, 4);   // (128, 25, 4)
  delay_split_lds<<<gd, 512, RR_ * LSTR_ * sizeof(float), stream>>>(x, delays, A3);

  // 256x256 tiles: (64000/256) * (1024/256) = 250 * 4 = 1000 blocks
  gemm_split<<<1000, 512, 131072, stream>>>(A3, Bt, Iin);

  recurrent_w<<<B_, 512, 0, stream>>>(Iin, wrecT, woutT,
                                      alpha, rho, beta_a, beta_out, out);
}

// Round 6
// 987.552 us; speedup vs baseline: 1.2085x; 1.2085x over previous
//
#include <hip/hip_runtime.h>
#include <stdint.h>

#define B_   128
#define T_   500
#define C_   700
#define CP_  704          // C padded to 16
#define H_   1024
#define O_   20
#define M_   (T_ * B_)    // 64000 rows, row = t*128 + b
#define KA_  (2 * CP_)    // 1408: A' = [hi | lo]
#define KB_  (3 * CP_)    // 2112: Bt = [hi | hi | lo]
#define NKSTEP_ (KB_ / 64)   // 33 K-steps of 64
#define SCALE_      256.0f
#define INV_SCALE2_ (1.0f / 65536.0f)
#define MAXD_ 30
#define TT_   20                       // t-rows produced per delay block
#define RR_   (TT_ + MAXD_)            // 50 source rows staged in LDS
#define CS_   176                      // channels per delay block (4-way split)
#define LSTR_ 180                      // LDS row stride

typedef _Float16 half8 __attribute__((ext_vector_type(8)));
typedef float    f32x4 __attribute__((ext_vector_type(4)));

// ---------------------------------------------------------------------------
// out[c*R + r] = (c < C) ? in[r*C + c] : 0   (fp32 transpose, zero-pad)
// Cpad > C appends zero rows (dummy-index target for padded spike lists).
__global__ __launch_bounds__(256) void transpose_pad(
    const float* __restrict__ in, float* __restrict__ out,
    int R, int C, int Cpad) {
  int idx = blockIdx.x * 256 + threadIdx.x;
  if (idx >= Cpad * R) return;
  int c = idx / R;
  int r = idx - c * R;
  out[idx] = (c < C) ? in[(size_t)r * C + c] : 0.0f;
}

// ---------------------------------------------------------------------------
// Bt[n][k]: k in [0,704) -> hi(w*256); [704,1408) -> hi; [1408,2112) -> lo
__global__ __launch_bounds__(256) void bt_prep(
    const float* __restrict__ w_in, _Float16* __restrict__ Bt) {
  int idx = blockIdx.x * 256 + threadIdx.x;   // over H_*KB_
  if (idx >= H_ * KB_) return;
  int n = idx / KB_;
  int k = idx - n * KB_;
  int blk = k / CP_;
  int c = k - blk * CP_;
  float v = (c < C_) ? w_in[(size_t)n * C_ + c] * SCALE_ : 0.0f;
  _Float16 hi = (_Float16)v;
  Bt[idx] = (blk == 2) ? (_Float16)(v - (float)hi) : hi;
}

// ---------------------------------------------------------------------------
// R10 delay gather (FROZEN, control).
__global__ __launch_bounds__(512) void delay_split_lds(
    const float* __restrict__ x, const int* __restrict__ delays,
    _Float16* __restrict__ A3) {
  extern __shared__ float xs[];          // [RR_][LSTR_] floats = 36000 B
  __shared__ int sdel[CS_];

  const int b   = blockIdx.x;            // 0..127
  const int t0  = blockIdx.y * TT_;      // 0,20,...,480
  const int c0  = blockIdx.z * CS_;      // 0,176,352,528
  const int tid = threadIdx.x;

  for (int c = tid; c < CS_; c += 512) {
    const int cc = c0 + c;
    sdel[c] = (cc < C_) ? delays[cc] : 0;
  }

  const int zr = (t0 < MAXD_) ? (MAXD_ - t0) : 0;
  const float* srcb = x + ((long)(b * T_ + t0) - MAXD_) * C_ + c0;
  for (int i = tid; i < RR_ * (CS_ / 4); i += 512) {
    const int r  = i / (CS_ / 4);
    const int q4 = (i - r * (CS_ / 4)) * 4;
    float4 v = {0.f, 0.f, 0.f, 0.f};
    if (r >= zr && c0 + q4 < C_)
      v = *(const float4*)(srcb + (long)r * C_ + q4);
    *(float4*)&xs[r * LSTR_ + q4] = v;
  }
  __syncthreads();

  for (int e = tid; e < TT_ * (CS_ / 8); e += 512) {
    const int tt = e / (CS_ / 8);
    const int cl = (e - tt * (CS_ / 8)) * 8;
    half8 hv, lv;
#pragma unroll
    for (int j = 0; j < 8; ++j) {
      const int c = cl + j;
      float vv = 0.f;
      if (c0 + c < C_)
        vv = xs[(tt + MAXD_ - sdel[c]) * LSTR_ + c] * SCALE_;
      const _Float16 hi = (_Float16)vv;
      hv[j] = hi;
      lv[j] = (_Float16)(vv - (float)hi);
    }
    _Float16* dst = A3 + (size_t)((t0 + tt) * B_ + b) * KA_ + c0 + cl;
    *(half8*)dst = hv;
    *((half8*)(dst + CP_)) = lv;
  }
}

// ---------------------------------------------------------------------------
__device__ __forceinline__ void gload16(const void* g, const void* l) {
  __builtin_amdgcn_global_load_lds(
      (const __attribute__((address_space(1))) void*)(uintptr_t)g,
      (__attribute__((address_space(3))) void*)(uint32_t)(uintptr_t)l,
      16, 0, 0);
}

// ---------------------------------------------------------------------------
// R11 4-phase GEMM (FROZEN, control).
__global__ __launch_bounds__(512, 1) void gemm_split(
    const _Float16* __restrict__ A3, const _Float16* __restrict__ Bt,
    float* __restrict__ Cm) {
  extern __shared__ __align__(16) _Float16 lds[];   // 131072 B
  _Float16* As = lds;                // [2][256*64]
  _Float16* Bs = lds + 2 * 16384;    // [2][256*64]

  const int tid  = threadIdx.x;
  const int wave = tid >> 6, lane = tid & 63;

  const int d = blockIdx.x;
  const int g = (d & 7) * 125 + (d >> 3);
  const int row0 = (g >> 2) * 256;        // M panel (0..249)
  const int col0 = (g & 3) * 256;         // N panel (0..3)

  const int r = lane & 15, q = lane >> 4;
  const int wm = wave >> 2, wn = wave & 3;

  int asrcB[4], bsrcB[4], auoff[4];
#pragma unroll
  for (int j = 0; j < 4; ++j) {
    const int i   = j * 512 + wave * 64 + lane;
    const int row = i >> 3, c = i & 7;
    asrcB[j] = (row0 + row) * KA_ + ((c ^ (row & 7)) * 8);
    bsrcB[j] = (col0 + row) * KB_ + ((c ^ (row & 7)) * 8);
    auoff[j] = (j * 512 + wave * 64) * 8;   // wave-uniform LDS base (halfs)
  }

  int aRow[8], bRow[4];
#pragma unroll
  for (int m = 0; m < 8; ++m) aRow[m] = (wm * 128 + m * 16 + r) * 64;
#pragma unroll
  for (int n = 0; n < 4; ++n) bRow[n] = (wn * 64 + n * 16 + r) * 64;
  const int sl0 = (q ^ (r & 7)) * 8;      // ks=0 slot
  const int sl1 = sl0 ^ 32;               // ks=1 slot

  f32x4 acc[8][4] = {};

#pragma unroll
  for (int j = 0; j < 4; ++j) gload16(A3 + asrcB[j], As + auoff[j]);
#pragma unroll
  for (int j = 0; j < 4; ++j) gload16(Bt + bsrcB[j], Bs + auoff[j]);
  asm volatile("s_waitcnt vmcnt(0)" ::: "memory");
  __syncthreads();

#define PHASE_BAR() do {                                   \
    __builtin_amdgcn_sched_barrier(0);                     \
    __builtin_amdgcn_s_barrier();                          \
    __builtin_amdgcn_sched_barrier(0);                     \
  } while (0)

#define MFMA16(AF, BF) do {                                \
    __builtin_amdgcn_s_setprio(1);                         \
    _Pragma("unroll")                                      \
    for (int mm = 0; mm < 4; ++mm)                         \
      _Pragma("unroll")                                    \
      for (int nn = 0; nn < 4; ++nn)                       \
        ACCROW[mm][nn] = __builtin_amdgcn_mfma_f32_16x16x32_f16( \
            AF[mm], BF[nn], ACCROW[mm][nn], 0, 0, 0);      \
    __builtin_amdgcn_s_setprio(0);                         \
  } while (0)

  for (int k = 0; k < NKSTEP_; ++k) {
    const int cbuf = (k & 1) * 16384;
    const int nbuf = ((k + 1) & 1) * 16384;
    const int k0n  = (k + 1) * 64;
    const int kAn  = (k0n < KA_) ? k0n : k0n - KA_;
    const bool st  = (k + 1 < NKSTEP_);

    half8 a0[4], a1[4], b0[4], b1[4];

#pragma unroll
    for (int m = 0; m < 4; ++m) a0[m] = *(const half8*)&As[cbuf + aRow[m] + sl0];
#pragma unroll
    for (int n = 0; n < 4; ++n) b0[n] = *(const half8*)&Bs[cbuf + bRow[n] + sl0];
    if (st) {
#pragma unroll
      for (int j = 0; j < 4; ++j) gload16(A3 + asrcB[j] + kAn, As + nbuf + auoff[j]);
    }
    PHASE_BAR();
    {
      f32x4 (&ACCROW)[4][4] = *reinterpret_cast<f32x4(*)[4][4]>(&acc[0]);
      MFMA16(a0, b0);
    }
    PHASE_BAR();

#pragma unroll
    for (int m = 0; m < 4; ++m) a1[m] = *(const half8*)&As[cbuf + aRow[m + 4] + sl0];
    if (st) {
      gload16(Bt + bsrcB[0] + k0n, Bs + nbuf + auoff[0]);
      gload16(Bt + bsrcB[1] + k0n, Bs + nbuf + auoff[1]);
    }
    PHASE_BAR();
    {
      f32x4 (&ACCROW)[4][4] = *reinterpret_cast<f32x4(*)[4][4]>(&acc[4]);
      MFMA16(a1, b0);
    }
    PHASE_BAR();

#pragma unroll
    for (int m = 0; m < 4; ++m) a0[m] = *(const half8*)&As[cbuf + aRow[m] + sl1];
#pragma unroll
    for (int n = 0; n < 4; ++n) b1[n] = *(const half8*)&Bs[cbuf + bRow[n] + sl1];
    if (st) {
      gload16(Bt + bsrcB[2] + k0n, Bs + nbuf + auoff[2]);
      gload16(Bt + bsrcB[3] + k0n, Bs + nbuf + auoff[3]);
    }
    PHASE_BAR();
    {
      f32x4 (&ACCROW)[4][4] = *reinterpret_cast<f32x4(*)[4][4]>(&acc[0]);
      MFMA16(a0, b1);
    }
    PHASE_BAR();

#pragma unroll
    for (int m = 0; m < 4; ++m) a1[m] = *(const half8*)&As[cbuf + aRow[m + 4] + sl1];
    PHASE_BAR();
    {
      f32x4 (&ACCROW)[4][4] = *reinterpret_cast<f32x4(*)[4][4]>(&acc[4]);
      MFMA16(a1, b1);
    }
    asm volatile("s_waitcnt vmcnt(0)" ::: "memory");
    PHASE_BAR();
  }
#undef MFMA16
#undef PHASE_BAR

#pragma unroll
  for (int m = 0; m < 8; ++m) {
    const int mrow = row0 + wm * 128 + m * 16 + q * 4;
#pragma unroll
    for (int n = 0; n < 4; ++n) {
      const int ncol = col0 + wn * 64 + n * 16 + r;
      float* cp = Cm + (size_t)mrow * H_ + ncol;
#pragma unroll
      for (int rg = 0; rg < 4; ++rg)
        cp[(size_t)rg * H_] = acc[m][n][rg] * INV_SCALE2_;
    }
  }
}

// ---------------------------------------------------------------------------
// R13 recurrent: R8 streaming skeleton (256 thr / 4 waves, float4 Iin lane
// reads, 4-deep reg prefetch) + list-gather with the R12 overheads removed:
//  - all 4 wave-list counts in ONE int4 LDS broadcast (1 lgkm wait, not 8)
//  - zero-spike fast path skips the gather entirely (R5 counters: kernel is
//    90% stall; spike work ~nil -> per-step fixed overhead is everything)
//  - 4-wave barrier (R12's 8-wave barrier halved)
//  - compaction: 4 ballots + popc prefix, no serial readlane chain
__global__ __launch_bounds__(256, 1) void recurrent_w(
    const float* __restrict__ Iin,   // [M_][H_], row = t*128 + b
    const float* __restrict__ wrecT, // [(H_+1)][H_], row 1024 = zeros
    const float* __restrict__ woutT, // [(H_+1)][O_], row 1024 = zeros
    const float* __restrict__ alpha, const float* __restrict__ rho,
    const float* __restrict__ beta_a, const float* __restrict__ beta_out,
    float* __restrict__ out) {
  const int b    = blockIdx.x;
  const int tid  = threadIdx.x;     // 0..255
  const int wv   = tid >> 6, lane = tid & 63;
  const int h0   = tid * 4;         // 4 neurons per thread

  __shared__ __align__(16) unsigned short slist[2][4][264];
  __shared__ __align__(16) int scnt[2][4];

  float vv[4], av[4];
#pragma unroll
  for (int j = 0; j < 4; ++j) { vv[j] = 0.f; av[j] = 0.f; }
  unsigned pnib = 0u;               // own 4 prev-spike bits

  const float al = alpha[h0], al1 = 1.0f - al;
  const float rh = rho[h0],   rh1 = 1.0f - rh;
  const float ba = beta_a[h0];

  const int olane = (tid < O_) ? tid : 0;
  float bo = 0.f, vo = 0.f, osum = 0.f;
  if (tid < O_) bo = beta_out[tid];

  if (tid < 8) scnt[tid >> 2][tid & 3] = 0;   // zero both count buffers
  __syncthreads();

  const float* base = Iin + (size_t)b * H_ + h0;

  // prime 4-deep Iin prefetch: one float4 per t = 0,1,2,3
  float4 pA = *(const float4*)(base + (size_t)0 * (B_ * H_));
  float4 pB = *(const float4*)(base + (size_t)1 * (B_ * H_));
  float4 pC = *(const float4*)(base + (size_t)2 * (B_ * H_));
  float4 pD = *(const float4*)(base + (size_t)3 * (B_ * H_));

  int cb = 0;

#define LIF_STEP(NR, TCUR)                                                    \
  {                                                                           \
    float I[4] = {NR.x, NR.y, NR.z, NR.w};                                    \
    float io = 0.f;                                                           \
    const int4 cn = *(const int4*)&scnt[cb][0];                               \
    if ((cn.x | cn.y | cn.z | cn.w) != 0) {                                   \
      _Pragma("unroll")                                                       \
      for (int w = 0; w < 4; ++w) {                                           \
        const int n = (w == 0) ? cn.x : (w == 1) ? cn.y                       \
                     : (w == 2) ? cn.z : cn.w;                                \
        const unsigned short* L = &slist[cb][w][0];                           \
        for (int i = 0; i < n; i += 8) {                                      \
          const ushort4 ia = *(const ushort4*)&L[i];                          \
          const ushort4 ib = *(const ushort4*)&L[i + 4];                      \
          const float4 w0 = *(const float4*)(wrecT + ((size_t)ia.x << 10) + h0); \
          const float4 w1 = *(const float4*)(wrecT + ((size_t)ia.y << 10) + h0); \
          const float4 w2 = *(const float4*)(wrecT + ((size_t)ia.z << 10) + h0); \
          const float4 w3 = *(const float4*)(wrecT + ((size_t)ia.w << 10) + h0); \
          const float4 w4 = *(const float4*)(wrecT + ((size_t)ib.x << 10) + h0); \
          const float4 w5 = *(const float4*)(wrecT + ((size_t)ib.y << 10) + h0); \
          const float4 w6 = *(const float4*)(wrecT + ((size_t)ib.z << 10) + h0); \
          const float4 w7 = *(const float4*)(wrecT + ((size_t)ib.w << 10) + h0); \
          const float o0 = woutT[(size_t)ia.x * O_ + olane];                  \
          const float o1 = woutT[(size_t)ia.y * O_ + olane];                  \
          const float o2 = woutT[(size_t)ia.z * O_ + olane];                  \
          const float o3 = woutT[(size_t)ia.w * O_ + olane];                  \
          const float o4 = woutT[(size_t)ib.x * O_ + olane];                  \
          const float o5 = woutT[(size_t)ib.y * O_ + olane];                  \
          const float o6 = woutT[(size_t)ib.z * O_ + olane];                  \
          const float o7 = woutT[(size_t)ib.w * O_ + olane];                  \
          _Pragma("unroll")                                                   \
          for (int j = 0; j < 4; ++j)                                         \
            I[j] += ((w0[j] + w1[j]) + (w2[j] + w3[j]))                       \
                  + ((w4[j] + w5[j]) + (w6[j] + w7[j]));                      \
          io += ((o0 + o1) + (o2 + o3)) + ((o4 + o5) + (o6 + o7));            \
        }                                                                     \
      }                                                                       \
    }                                                                         \
    {                                                                         \
      const int tp = ((TCUR) + 4 <= T_ - 1) ? (TCUR) + 4 : (T_ - 1);          \
      NR = *(const float4*)(base + (size_t)tp * (B_ * H_));                   \
    }                                                                         \
    vo = bo * vo + (1.0f - bo) * io;                                          \
    osum += vo;                                                               \
    unsigned nib = 0u;                                                        \
    _Pragma("unroll")                                                         \
    for (int j = 0; j < 4; ++j) {                                             \
      const float vg = (pnib & (1u << j)) ? 0.f : vv[j];                      \
      const float vn = al * vg + al1 * (I[j] - av[j]);                        \
      av[j] = rh * av[j] + rh1 * fmaf(ba, vn, (vn > 1.0f) ? 1.0f : 0.0f);     \
      vv[j] = vn;                                                             \
      nib |= (vn > 1.0f) ? (1u << j) : 0u;                                    \
    }                                                                         \
    pnib = nib;                                                               \
    {                                                                         \
      const unsigned long long bl0 = __ballot(nib & 1u);                      \
      const unsigned long long bl1 = __ballot(nib & 2u);                      \
      const unsigned long long bl2 = __ballot(nib & 4u);                      \
      const unsigned long long bl3 = __ballot(nib & 8u);                      \
      const unsigned long long below = (1ull << lane) - 1ull;                 \
      int pos = (int)__popcll(bl0 & below) + (int)__popcll(bl1 & below)       \
              + (int)__popcll(bl2 & below) + (int)__popcll(bl3 & below);      \
      unsigned short* Lw = &slist[cb ^ 1][wv][0];                             \
      if (nib & 1u) { Lw[pos] = (unsigned short)h0;       pos += 1; }         \
      if (nib & 2u) { Lw[pos] = (unsigned short)(h0 + 1); pos += 1; }         \
      if (nib & 4u) { Lw[pos] = (unsigned short)(h0 + 2); pos += 1; }         \
      if (nib & 8u) { Lw[pos] = (unsigned short)(h0 + 3); }                   \
      if (lane == 63) {                                                       \
        const int tot = (int)__popcll(bl0) + (int)__popcll(bl1)               \
                      + (int)__popcll(bl2) + (int)__popcll(bl3);              \
        const int pd  = (tot + 7) & ~7;                                       \
        for (int z = tot; z < pd; ++z) Lw[z] = (unsigned short)H_;            \
        scnt[cb ^ 1][wv] = pd;                                                \
      }                                                                       \
    }                                                                         \
    __syncthreads();                                                          \
    cb ^= 1;                                                                  \
  }

  for (int k = 0; k < T_ / 4; ++k) {
    const int t0 = k * 4;
    LIF_STEP(pA, t0 + 0)
    LIF_STEP(pB, t0 + 1)
    LIF_STEP(pC, t0 + 2)
    LIF_STEP(pD, t0 + 3)
  }
#undef LIF_STEP

  // epilogue: readout contribution of the final spike set S(T-1)
  {
    float io = 0.f;
    for (int w = 0; w < 4; ++w) {
      const int n = scnt[cb][w];
      for (int i = 0; i < n; ++i)
        io += woutT[(size_t)slist[cb][w][i] * O_ + olane];
    }
    vo = bo * vo + (1.0f - bo) * io;
    osum += vo;
  }

  if (tid < O_) out[(size_t)b * O_ + tid] = osum / (float)T_;
}

// ---------------------------------------------------------------------------
extern "C" void kernel_launch(void* const* d_in, const int* in_sizes, int n_in,
                              void* d_out, int out_size, void* d_ws, size_t ws_size,
                              hipStream_t stream) {
  const float* x        = (const float*)d_in[0];
  const int*   delays   = (const int*)d_in[1];
  const float* w_in     = (const float*)d_in[2];
  const float* w_rec    = (const float*)d_in[3];
  const float* w_out    = (const float*)d_in[4];
  const float* alpha    = (const float*)d_in[5];
  const float* rho      = (const float*)d_in[6];
  const float* beta_a   = (const float*)d_in[7];
  const float* beta_out = (const float*)d_in[8];

  float* ws    = (float*)d_ws;
  float* wrecT = ws;                                      // (H+1)*H fp32
  float* woutT = wrecT + (size_t)(H_ + 1) * H_;           // (H+1)*O fp32
  float* Iin   = woutT + (size_t)(H_ + 1) * O_;           // M*H fp32
  _Float16* A3 = (_Float16*)(Iin + (size_t)M_ * H_);      // M*KA fp16
  _Float16* Bt = A3 + (size_t)M_ * KA_;                   // H*KB fp16
  float* out   = (float*)d_out;

  // Cpad = H_+1 appends a zero row at index 1024 (dummy-index target).
  transpose_pad<<<((H_ + 1) * H_) / 256, 256, 0, stream>>>(
      w_rec, wrecT, H_, H_, H_ + 1);
  transpose_pad<<<((H_ + 1) * O_ + 255) / 256, 256, 0, stream>>>(
      w_out, woutT, O_, H_, H_ + 1);
  bt_prep<<<(H_ * KB_) / 256, 256, 0, stream>>>(w_in, Bt);

  dim3 gd(B_, T_ / TT_, 4);   // (128, 25, 4)
  delay_split_lds<<<gd, 512, RR_ * LSTR_ * sizeof(float), stream>>>(x, delays, A3);

  // 256x256 tiles: (64000/256) * (1024/256) = 250 * 4 = 1000 blocks
  gemm_split<<<1000, 512, 131072, stream>>>(A3, Bt, Iin);

  recurrent_w<<<B_, 256, 0, stream>>>(Iin, wrecT, woutT,
                                      alpha, rho, beta_a, beta_out, out);
}

// Round 7
// 826.144 us; speedup vs baseline: 1.4446x; 1.1954x over previous
//
#include <hip/hip_runtime.h>
#include <stdint.h>

#define B_   128
#define T_   500
#define C_   700
#define CP_  704          // C padded to 16
#define H_   1024
#define O_   20
#define M_   (T_ * B_)    // 64000 rows, row = t*128 + b
#define KA_  (2 * CP_)    // 1408: A' = [hi | lo]
#define KB_  (3 * CP_)    // 2112: Bt = [hi | hi | lo]
#define NKSTEP_ (KB_ / 64)   // 33 K-steps of 64
#define SCALE_      256.0f
#define INV_SCALE2_ (1.0f / 65536.0f)
#define MAXD_ 30
#define TT_   20                       // t-rows produced per delay block
#define RR_   (TT_ + MAXD_)            // 50 source rows staged in LDS
#define CS_   176                      // channels per delay block (4-way split)
#define LSTR_ 180                      // LDS row stride

typedef _Float16 half8 __attribute__((ext_vector_type(8)));
typedef float    f32x4 __attribute__((ext_vector_type(4)));

// ---------------------------------------------------------------------------
// out[c*R + r] = (c < C) ? in[r*C + c] : 0   (fp32 transpose, zero-pad)
__global__ __launch_bounds__(256) void transpose_pad(
    const float* __restrict__ in, float* __restrict__ out,
    int R, int C, int Cpad) {
  int idx = blockIdx.x * 256 + threadIdx.x;
  if (idx >= Cpad * R) return;
  int c = idx / R;
  int r = idx - c * R;
  out[idx] = (c < C) ? in[(size_t)r * C + c] : 0.0f;
}

// ---------------------------------------------------------------------------
// Bt[n][k]: k in [0,704) -> hi(w*256); [704,1408) -> hi; [1408,2112) -> lo
__global__ __launch_bounds__(256) void bt_prep(
    const float* __restrict__ w_in, _Float16* __restrict__ Bt) {
  int idx = blockIdx.x * 256 + threadIdx.x;   // over H_*KB_
  if (idx >= H_ * KB_) return;
  int n = idx / KB_;
  int k = idx - n * KB_;
  int blk = k / CP_;
  int c = k - blk * CP_;
  float v = (c < C_) ? w_in[(size_t)n * C_ + c] * SCALE_ : 0.0f;
  _Float16 hi = (_Float16)v;
  Bt[idx] = (blk == 2) ? (_Float16)(v - (float)hi) : hi;
}

// ---------------------------------------------------------------------------
// R14 delay gather: SAME body as R10, but XCD-locality block remap.
// 1D grid of 12800 = 8*1600 blocks; id -> v = (id&7)*1600 + id>>3 (bijective).
// v decodes as (t-tile fastest, then c-block, then b), so the ~13 consecutive
// same-XCD blocks are ADJACENT t-tiles of one (c,b): the 30-row staging halo
// (2.5x read amplification) becomes an L2 hit instead of an HBM re-fetch --
// the same mechanism that cut gemm FETCH 1.07 GB -> 239 MB in R7.
__global__ __launch_bounds__(512) void delay_split_lds(
    const float* __restrict__ x, const int* __restrict__ delays,
    _Float16* __restrict__ A3) {
  extern __shared__ float xs[];          // [RR_][LSTR_] floats = 36000 B
  __shared__ int sdel[CS_];

  const int id   = blockIdx.x;           // 0..12799
  const int v    = (id & 7) * 1600 + (id >> 3);
  const int ttb  = v % 25;               // t-tile
  const int rest = v / 25;
  const int b    = rest >> 2;            // 0..127
  const int t0   = ttb * TT_;            // 0,20,...,480
  const int c0   = (rest & 3) * CS_;     // 0,176,352,528
  const int tid  = threadIdx.x;

  for (int c = tid; c < CS_; c += 512) {
    const int cc = c0 + c;
    sdel[c] = (cc < C_) ? delays[cc] : 0;
  }

  const int zr = (t0 < MAXD_) ? (MAXD_ - t0) : 0;
  const float* srcb = x + ((long)(b * T_ + t0) - MAXD_) * C_ + c0;
  for (int i = tid; i < RR_ * (CS_ / 4); i += 512) {
    const int r  = i / (CS_ / 4);
    const int q4 = (i - r * (CS_ / 4)) * 4;
    float4 vv = {0.f, 0.f, 0.f, 0.f};
    if (r >= zr && c0 + q4 < C_)
      vv = *(const float4*)(srcb + (long)r * C_ + q4);
    *(float4*)&xs[r * LSTR_ + q4] = vv;
  }
  __syncthreads();

  for (int e = tid; e < TT_ * (CS_ / 8); e += 512) {
    const int tt = e / (CS_ / 8);
    const int cl = (e - tt * (CS_ / 8)) * 8;
    half8 hv, lv;
#pragma unroll
    for (int j = 0; j < 8; ++j) {
      const int c = cl + j;
      float vv = 0.f;
      if (c0 + c < C_)
        vv = xs[(tt + MAXD_ - sdel[c]) * LSTR_ + c] * SCALE_;
      const _Float16 hi = (_Float16)vv;
      hv[j] = hi;
      lv[j] = (_Float16)(vv - (float)hi);
    }
    _Float16* dst = A3 + (size_t)((t0 + tt) * B_ + b) * KA_ + c0 + cl;
    *(half8*)dst = hv;
    *((half8*)(dst + CP_)) = lv;
  }
}

// ---------------------------------------------------------------------------
__device__ __forceinline__ void gload16(const void* g, const void* l) {
  __builtin_amdgcn_global_load_lds(
      (const __attribute__((address_space(1))) void*)(uintptr_t)g,
      (__attribute__((address_space(3))) void*)(uint32_t)(uintptr_t)l,
      16, 0, 0);
}

// ---------------------------------------------------------------------------
// R11 4-phase GEMM (FROZEN, control).
__global__ __launch_bounds__(512, 1) void gemm_split(
    const _Float16* __restrict__ A3, const _Float16* __restrict__ Bt,
    float* __restrict__ Cm) {
  extern __shared__ __align__(16) _Float16 lds[];   // 131072 B
  _Float16* As = lds;                // [2][256*64]
  _Float16* Bs = lds + 2 * 16384;    // [2][256*64]

  const int tid  = threadIdx.x;
  const int wave = tid >> 6, lane = tid & 63;

  const int d = blockIdx.x;
  const int g = (d & 7) * 125 + (d >> 3);
  const int row0 = (g >> 2) * 256;        // M panel (0..249)
  const int col0 = (g & 3) * 256;         // N panel (0..3)

  const int r = lane & 15, q = lane >> 4;
  const int wm = wave >> 2, wn = wave & 3;

  int asrcB[4], bsrcB[4], auoff[4];
#pragma unroll
  for (int j = 0; j < 4; ++j) {
    const int i   = j * 512 + wave * 64 + lane;
    const int row = i >> 3, c = i & 7;
    asrcB[j] = (row0 + row) * KA_ + ((c ^ (row & 7)) * 8);
    bsrcB[j] = (col0 + row) * KB_ + ((c ^ (row & 7)) * 8);
    auoff[j] = (j * 512 + wave * 64) * 8;   // wave-uniform LDS base (halfs)
  }

  int aRow[8], bRow[4];
#pragma unroll
  for (int m = 0; m < 8; ++m) aRow[m] = (wm * 128 + m * 16 + r) * 64;
#pragma unroll
  for (int n = 0; n < 4; ++n) bRow[n] = (wn * 64 + n * 16 + r) * 64;
  const int sl0 = (q ^ (r & 7)) * 8;      // ks=0 slot
  const int sl1 = sl0 ^ 32;               // ks=1 slot

  f32x4 acc[8][4] = {};

#pragma unroll
  for (int j = 0; j < 4; ++j) gload16(A3 + asrcB[j], As + auoff[j]);
#pragma unroll
  for (int j = 0; j < 4; ++j) gload16(Bt + bsrcB[j], Bs + auoff[j]);
  asm volatile("s_waitcnt vmcnt(0)" ::: "memory");
  __syncthreads();

#define PHASE_BAR() do {                                   \
    __builtin_amdgcn_sched_barrier(0);                     \
    __builtin_amdgcn_s_barrier();                          \
    __builtin_amdgcn_sched_barrier(0);                     \
  } while (0)

#define MFMA16(AF, BF) do {                                \
    __builtin_amdgcn_s_setprio(1);                         \
    _Pragma("unroll")                                      \
    for (int mm = 0; mm < 4; ++mm)                         \
      _Pragma("unroll")                                    \
      for (int nn = 0; nn < 4; ++nn)                       \
        ACCROW[mm][nn] = __builtin_amdgcn_mfma_f32_16x16x32_f16( \
            AF[mm], BF[nn], ACCROW[mm][nn], 0, 0, 0);      \
    __builtin_amdgcn_s_setprio(0);                         \
  } while (0)

  for (int k = 0; k < NKSTEP_; ++k) {
    const int cbuf = (k & 1) * 16384;
    const int nbuf = ((k + 1) & 1) * 16384;
    const int k0n  = (k + 1) * 64;
    const int kAn  = (k0n < KA_) ? k0n : k0n - KA_;
    const bool st  = (k + 1 < NKSTEP_);

    half8 a0[4], a1[4], b0[4], b1[4];

#pragma unroll
    for (int m = 0; m < 4; ++m) a0[m] = *(const half8*)&As[cbuf + aRow[m] + sl0];
#pragma unroll
    for (int n = 0; n < 4; ++n) b0[n] = *(const half8*)&Bs[cbuf + bRow[n] + sl0];
    if (st) {
#pragma unroll
      for (int j = 0; j < 4; ++j) gload16(A3 + asrcB[j] + kAn, As + nbuf + auoff[j]);
    }
    PHASE_BAR();
    {
      f32x4 (&ACCROW)[4][4] = *reinterpret_cast<f32x4(*)[4][4]>(&acc[0]);
      MFMA16(a0, b0);
    }
    PHASE_BAR();

#pragma unroll
    for (int m = 0; m < 4; ++m) a1[m] = *(const half8*)&As[cbuf + aRow[m + 4] + sl0];
    if (st) {
      gload16(Bt + bsrcB[0] + k0n, Bs + nbuf + auoff[0]);
      gload16(Bt + bsrcB[1] + k0n, Bs + nbuf + auoff[1]);
    }
    PHASE_BAR();
    {
      f32x4 (&ACCROW)[4][4] = *reinterpret_cast<f32x4(*)[4][4]>(&acc[4]);
      MFMA16(a1, b0);
    }
    PHASE_BAR();

#pragma unroll
    for (int m = 0; m < 4; ++m) a0[m] = *(const half8*)&As[cbuf + aRow[m] + sl1];
#pragma unroll
    for (int n = 0; n < 4; ++n) b1[n] = *(const half8*)&Bs[cbuf + bRow[n] + sl1];
    if (st) {
      gload16(Bt + bsrcB[2] + k0n, Bs + nbuf + auoff[2]);
      gload16(Bt + bsrcB[3] + k0n, Bs + nbuf + auoff[3]);
    }
    PHASE_BAR();
    {
      f32x4 (&ACCROW)[4][4] = *reinterpret_cast<f32x4(*)[4][4]>(&acc[0]);
      MFMA16(a0, b1);
    }
    PHASE_BAR();

#pragma unroll
    for (int m = 0; m < 4; ++m) a1[m] = *(const half8*)&As[cbuf + aRow[m + 4] + sl1];
    PHASE_BAR();
    {
      f32x4 (&ACCROW)[4][4] = *reinterpret_cast<f32x4(*)[4][4]>(&acc[4]);
      MFMA16(a1, b1);
    }
    asm volatile("s_waitcnt vmcnt(0)" ::: "memory");
    PHASE_BAR();
  }
#undef MFMA16
#undef PHASE_BAR

#pragma unroll
  for (int m = 0; m < 8; ++m) {
    const int mrow = row0 + wm * 128 + m * 16 + q * 4;
#pragma unroll
    for (int n = 0; n < 4; ++n) {
      const int ncol = col0 + wn * 64 + n * 16 + r;
      float* cp = Cm + (size_t)mrow * H_ + ncol;
#pragma unroll
      for (int rg = 0; rg < 4; ++rg)
        cp[(size_t)rg * H_] = acc[m][n][rg] * INV_SCALE2_;
    }
  }
}

// ---------------------------------------------------------------------------
// R8 recurrent, REVERTED VERBATIM (proven <= 282 us in R4; list-based R12/R13
// variants were 554/340 -- latency chain, not scan VALU, is the cost).
// 4-wave column split, 256 threads per sample, 4 neurons/thread; spike bitmap
// exchanged via double-buffered LDS nibbles; ballot/readlane batched gather.
#define GATHER_LIF_STEP(NR, TCUR)                                             \
  {                                                                           \
    float Iv[4];                                                              \
    Iv[0] = NR.x; Iv[1] = NR.y; Iv[2] = NR.z; Iv[3] = NR.w;                   \
    float io = 0.f;                                                           \
    unsigned long long lm = __ballot(sword != 0u);                            \
    unsigned w = 0u;                                                          \
    int lcur = 0;                                                             \
    while ((lm != 0ull) | (w != 0u)) {                                        \
      int hA, hB, hC, hD;                                                     \
      float sB, sC, sD;                                                       \
      if (w == 0u) {                                                          \
        lcur = (int)__builtin_ctzll(lm); lm &= lm - 1ull;                     \
        w = ((unsigned)__builtin_amdgcn_readlane((int)sword, lcur)) & 0xFFFFu;\
      }                                                                       \
      hA = lcur * 16 + (int)__builtin_ctz(w); w &= w - 1u;                    \
      if (w == 0u && lm != 0ull) {                                            \
        lcur = (int)__builtin_ctzll(lm); lm &= lm - 1ull;                     \
        w = ((unsigned)__builtin_amdgcn_readlane((int)sword, lcur)) & 0xFFFFu;\
      }                                                                       \
      if (w != 0u) { hB = lcur*16 + (int)__builtin_ctz(w); w &= w-1u; sB=1.f;}\
      else         { hB = hA; sB = 0.f; }                                     \
      if (w == 0u && lm != 0ull) {                                            \
        lcur = (int)__builtin_ctzll(lm); lm &= lm - 1ull;                     \
        w = ((unsigned)__builtin_amdgcn_readlane((int)sword, lcur)) & 0xFFFFu;\
      }                                                                       \
      if (w != 0u) { hC = lcur*16 + (int)__builtin_ctz(w); w &= w-1u; sC=1.f;}\
      else         { hC = hA; sC = 0.f; }                                     \
      if (w == 0u && lm != 0ull) {                                            \
        lcur = (int)__builtin_ctzll(lm); lm &= lm - 1ull;                     \
        w = ((unsigned)__builtin_amdgcn_readlane((int)sword, lcur)) & 0xFFFFu;\
      }                                                                       \
      if (w != 0u) { hD = lcur*16 + (int)__builtin_ctz(w); w &= w-1u; sD=1.f;}\
      else         { hD = hA; sD = 0.f; }                                     \
      const float4 wA = *(const float4*)(wrecT + (size_t)hA * H_ + h0);       \
      const float4 wB = *(const float4*)(wrecT + (size_t)hB * H_ + h0);       \
      const float4 wC = *(const float4*)(wrecT + (size_t)hC * H_ + h0);       \
      const float4 wD = *(const float4*)(wrecT + (size_t)hD * H_ + h0);       \
      const float oA = woutT[(size_t)hA * O_ + olane];                        \
      const float oB = woutT[(size_t)hB * O_ + olane];                        \
      const float oC = woutT[(size_t)hC * O_ + olane];                        \
      const float oD = woutT[(size_t)hD * O_ + olane];                        \
      Iv[0] += wA.x; Iv[1] += wA.y; Iv[2] += wA.z; Iv[3] += wA.w;             \
      io += oA;                                                               \
      Iv[0] = fmaf(sB, wB.x, Iv[0]); Iv[1] = fmaf(sB, wB.y, Iv[1]);           \
      Iv[2] = fmaf(sB, wB.z, Iv[2]); Iv[3] = fmaf(sB, wB.w, Iv[3]);           \
      io = fmaf(sB, oB, io);                                                  \
      Iv[0] = fmaf(sC, wC.x, Iv[0]); Iv[1] = fmaf(sC, wC.y, Iv[1]);           \
      Iv[2] = fmaf(sC, wC.z, Iv[2]); Iv[3] = fmaf(sC, wC.w, Iv[3]);           \
      io = fmaf(sC, oC, io);                                                  \
      Iv[0] = fmaf(sD, wD.x, Iv[0]); Iv[1] = fmaf(sD, wD.y, Iv[1]);           \
      Iv[2] = fmaf(sD, wD.z, Iv[2]); Iv[3] = fmaf(sD, wD.w, Iv[3]);           \
      io = fmaf(sD, oD, io);                                                  \
    }                                                                         \
    {                                                                         \
      const int tp = ((TCUR) + 4 <= T_ - 1) ? (TCUR) + 4 : (T_ - 1);          \
      NR = *(const float4*)(base + (size_t)tp * (B_ * H_));                   \
    }                                                                         \
    vo = bo * vo + (1.0f - bo) * io;                                          \
    osum += vo;                                                               \
    unsigned nib = 0u;                                                        \
    _Pragma("unroll")                                                         \
    for (int j = 0; j < 4; ++j) {                                             \
      const float vg = (pnib & (1u << j)) ? 0.f : vv[j];                      \
      const float vn = al * vg + al1 * (Iv[j] - av[j]);                       \
      av[j] = rh * av[j] + rh1 * fmaf(ba, vn, (vn > 1.0f) ? 1.0f : 0.0f);     \
      vv[j] = vn;                                                             \
      nib |= (vn > 1.0f) ? (1u << j) : 0u;                                    \
    }                                                                         \
    pnib = nib;                                                               \
    spb[nbuf][tid] = (unsigned char)nib;                                      \
    __syncthreads();                                                          \
    {                                                                         \
      const unsigned w32 = *(const unsigned*)&spb[nbuf][lane * 4];            \
      sword = (w32 & 0xFu) | ((w32 >> 4) & 0xF0u) |                           \
              ((w32 >> 8) & 0xF00u) | ((w32 >> 12) & 0xF000u);                \
    }                                                                         \
    nbuf ^= 1;                                                                \
  }

__global__ __launch_bounds__(256, 1) void recurrent_w(
    const float* __restrict__ Iin,   // [M_][H_], row = t*128 + b
    const float* __restrict__ wrecT, // [H_][H_]  wrecT[h'][h] = w_rec[h][h']
    const float* __restrict__ woutT, // [H_][O_]  woutT[h][o]  = w_out[o][h]
    const float* __restrict__ alpha, const float* __restrict__ rho,
    const float* __restrict__ beta_a, const float* __restrict__ beta_out,
    float* __restrict__ out) {
  const int b    = blockIdx.x;
  const int tid  = threadIdx.x;     // 0..255
  const int lane = tid & 63;
  const int h0   = tid * 4;         // 4 columns per thread

  __shared__ unsigned char spb[2][256];   // double-buffered spike nibbles

  float vv[4], av[4];
#pragma unroll
  for (int j = 0; j < 4; ++j) { vv[j] = 0.f; av[j] = 0.f; }
  unsigned sword = 0u;   // full-bitmap slice: bit j = neuron lane*16+j @ prev
  unsigned pnib  = 0u;   // this thread's own 4 prev-spike bits
  int nbuf = 0;

  const float al = alpha[h0], al1 = 1.0f - al;
  const float rh = rho[h0],   rh1 = 1.0f - rh;
  const float ba = beta_a[h0];

  const int olane = (tid < O_) ? tid : 0;
  float bo = 0.f, vo = 0.f, osum = 0.f;
  if (tid < O_) bo = beta_out[tid];

  const float* base = Iin + (size_t)b * H_ + h0;

  // prime 4-deep prefetch pipeline: one float4 per t = 0,1,2,3
  float4 pA = *(const float4*)(base + (size_t)0 * (B_ * H_));
  float4 pB = *(const float4*)(base + (size_t)1 * (B_ * H_));
  float4 pC = *(const float4*)(base + (size_t)2 * (B_ * H_));
  float4 pD = *(const float4*)(base + (size_t)3 * (B_ * H_));

  for (int k = 0; k < T_ / 4; ++k) {
    const int t0 = k * 4;
    GATHER_LIF_STEP(pA, t0 + 0)
    GATHER_LIF_STEP(pB, t0 + 1)
    GATHER_LIF_STEP(pC, t0 + 2)
    GATHER_LIF_STEP(pD, t0 + 3)
  }

  // epilogue: readout contribution of the final spike set S(T-1)
  {
    float io = 0.f;
    unsigned long long lm = __ballot(sword != 0u);
    while (lm != 0ull) {
      const int l = (int)__builtin_ctzll(lm); lm &= lm - 1ull;
      unsigned w = ((unsigned)__builtin_amdgcn_readlane((int)sword, l)) & 0xFFFFu;
      while (w != 0u) {
        const int j = (int)__builtin_ctz(w); w &= w - 1u;
        io += woutT[(size_t)(l * 16 + j) * O_ + olane];
      }
    }
    vo = bo * vo + (1.0f - bo) * io;
    osum += vo;
  }

  if (tid < O_) out[(size_t)b * O_ + tid] = osum / (float)T_;
}

// ---------------------------------------------------------------------------
extern "C" void kernel_launch(void* const* d_in, const int* in_sizes, int n_in,
                              void* d_out, int out_size, void* d_ws, size_t ws_size,
                              hipStream_t stream) {
  const float* x        = (const float*)d_in[0];
  const int*   delays   = (const int*)d_in[1];
  const float* w_in     = (const float*)d_in[2];
  const float* w_rec    = (const float*)d_in[3];
  const float* w_out    = (const float*)d_in[4];
  const float* alpha    = (const float*)d_in[5];
  const float* rho      = (const float*)d_in[6];
  const float* beta_a   = (const float*)d_in[7];
  const float* beta_out = (const float*)d_in[8];

  float* ws    = (float*)d_ws;
  float* wrecT = ws;                                 // H*H fp32
  float* woutT = wrecT + (size_t)H_ * H_;            // H*O fp32
  float* Iin   = woutT + (size_t)H_ * O_;            // M*H fp32
  _Float16* A3 = (_Float16*)(Iin + (size_t)M_ * H_); // M*KA fp16
  _Float16* Bt = A3 + (size_t)M_ * KA_;              // H*KB fp16
  float* out   = (float*)d_out;

  transpose_pad<<<(H_ * H_) / 256, 256, 0, stream>>>(w_rec, wrecT, H_, H_, H_);
  transpose_pad<<<(H_ * O_) / 256, 256, 0, stream>>>(w_out, woutT, O_, H_, H_);
  bt_prep<<<(H_ * KB_) / 256, 256, 0, stream>>>(w_in, Bt);

  // 1D grid with XCD-locality remap inside the kernel (12800 = 128*25*4)
  delay_split_lds<<<12800, 512, RR_ * LSTR_ * sizeof(float), stream>>>(
      x, delays, A3);

  // 256x256 tiles: (64000/256) * (1024/256) = 250 * 4 = 1000 blocks
  gemm_split<<<1000, 512, 131072, stream>>>(A3, Bt, Iin);

  recurrent_w<<<B_, 256, 0, stream>>>(Iin, wrecT, woutT,
                                      alpha, rho, beta_a, beta_out, out);
}